// Round 7
// baseline (1415.003 us; speedup 1.0000x reference)
//
#include <hip/hip_runtime.h>
#include <hip/hip_cooperative_groups.h>

namespace cg = cooperative_groups;

#define D 128
#define LDA 136   // bf16 elems per LDS row (+8 pad)

typedef __attribute__((ext_vector_type(8))) short bf16x8;
typedef __attribute__((ext_vector_type(4))) float f32x4;

static __device__ __forceinline__ unsigned short f2bf(float f) {
    unsigned u = __float_as_uint(f);
    unsigned r = 0x7fffu + ((u >> 16) & 1u);   // round-to-nearest-even
    return (unsigned short)((u + r) >> 16);
}
static __device__ __forceinline__ float bflo(unsigned u) { return __uint_as_float(u << 16); }
static __device__ __forceinline__ float bfhi(unsigned u) { return __uint_as_float(u & 0xffff0000u); }

// ---------------------------------------------------------------------------
// Cooperative mega-kernel: convert/zero -> hist -> alloc -> sort -> aggregate,
// with grid.sync() between phases. Zero LDS -> full occupancy for the
// latency-bound gather (round-5 lesson: never pair the gather with big LDS).
// __launch_bounds__(256,8): <=64 VGPR, 8 blocks/CU, grid 2048 co-resident.
// ---------------------------------------------------------------------------
template<bool BF16H>
__global__ __launch_bounds__(256, 8) void mega_kernel(
    const float* __restrict__ H, unsigned* __restrict__ Hb, int nh8,
    const float* __restrict__ W, unsigned short* __restrict__ Wt,
    const int* __restrict__ esrc, const int* __restrict__ edst, int E,
    int* __restrict__ counts, int* __restrict__ beg, int* __restrict__ deg,
    int* __restrict__ total, int* __restrict__ sorted,
    unsigned short* __restrict__ aggb, int n_dst)
{
    cg::grid_group grid = cg::this_grid();
    const int tid  = threadIdx.x;
    const int gtid = blockIdx.x * 256 + tid;
    const int nthr = gridDim.x * 256;
    const int lane = tid & 63;
    const int wid    = gtid >> 6;
    const int nwaves = nthr >> 6;

    // ---- Phase A: H->bf16, W transpose->bf16, zero counts & cursor ----
    if (BF16H) {
        const float4* h4 = (const float4*)H;
        for (int i = gtid; i < nh8; i += nthr) {
            float4 v0 = h4[(size_t)i * 2], v1 = h4[(size_t)i * 2 + 1];
            uint4 o;
            o.x = (unsigned)f2bf(v0.x) | ((unsigned)f2bf(v0.y) << 16);
            o.y = (unsigned)f2bf(v0.z) | ((unsigned)f2bf(v0.w) << 16);
            o.z = (unsigned)f2bf(v1.x) | ((unsigned)f2bf(v1.y) << 16);
            o.w = (unsigned)f2bf(v1.z) | ((unsigned)f2bf(v1.w) << 16);
            ((uint4*)Hb)[i] = o;
        }
    }
    for (int j = gtid; j < 16384; j += nthr) {    // Wt[n][k] = bf16(W[k][n])
        int k = j >> 7, n = j & 127;
        Wt[n * 128 + k] = f2bf(W[j]);
    }
    for (int j = gtid; j < n_dst; j += nthr) counts[j] = 0;
    if (gtid == 0) *total = 0;
    __threadfence();
    grid.sync();

    // ---- Phase B: histogram ----
    for (int e = gtid; e < E; e += nthr) atomicAdd(&counts[edst[e]], 1);
    __threadfence();
    grid.sync();

    // ---- Phase C: segment alloc (wave prefix + 1 atomic per 64 counts) ----
    {
        int nchunks = (n_dst + 63) / 64;
        for (int ch = wid; ch < nchunks; ch += nwaves) {
            int i = ch * 64 + lane;
            int c = (i < n_dst) ? counts[i] : 0;
            int x = c;
#pragma unroll
            for (int off = 1; off < 64; off <<= 1) {
                int t = __shfl_up(x, off, 64);
                if (lane >= off) x += t;
            }
            int base = 0;
            if (lane == 63) base = atomicAdd(total, x);
            base = __shfl(base, 63, 64);
            if (i < n_dst) { beg[i] = base + x - c; deg[i] = c; }
        }
    }
    __threadfence();
    grid.sync();

    // ---- Phase D: counting-sort scatter (counts down-cursor -> 0) ----
    for (int e = gtid; e < E; e += nthr) {
        int d = edst[e];
        int c = atomicAdd(&counts[d], -1);        // pre-value: deg..1
        sorted[beg[d] + c - 1] = esrc[e];
    }
    __threadfence();
    grid.sync();

    // ---- Phase E: pull aggregation, one wave per dst, bf16 out ----
    if (BF16H) {
        const uint4* Hb4 = (const uint4*)Hb;
        const int ql = lane & 15, quad = lane >> 4;
        for (int dst = wid; dst < n_dst; dst += nwaves) {
            int b0 = beg[dst], e0 = b0 + deg[dst];
            float acc[8] = {0, 0, 0, 0, 0, 0, 0, 0};
            for (int chunk = b0; chunk < e0; chunk += 64) {
                int m = e0 - chunk; if (m > 64) m = 64;
                int idx = (lane < m) ? sorted[chunk + lane] : 0;
                for (int j = 0; j < m; j += 4) {
                    int jj = j + quad;
                    int s = __shfl(idx, jj < m ? jj : m - 1);
                    uint4 hv = Hb4[(size_t)s * 16 + ql];
                    float w = (jj < m) ? 1.f : 0.f;
                    acc[0] += w * bflo(hv.x); acc[1] += w * bfhi(hv.x);
                    acc[2] += w * bflo(hv.y); acc[3] += w * bfhi(hv.y);
                    acc[4] += w * bflo(hv.z); acc[5] += w * bfhi(hv.z);
                    acc[6] += w * bflo(hv.w); acc[7] += w * bfhi(hv.w);
                }
            }
#pragma unroll
            for (int k = 0; k < 8; ++k) {
                acc[k] += __shfl_xor(acc[k], 16);
                acc[k] += __shfl_xor(acc[k], 32);
            }
            if (quad == 0) {
                uint4 o;
                o.x = (unsigned)f2bf(acc[0]) | ((unsigned)f2bf(acc[1]) << 16);
                o.y = (unsigned)f2bf(acc[2]) | ((unsigned)f2bf(acc[3]) << 16);
                o.z = (unsigned)f2bf(acc[4]) | ((unsigned)f2bf(acc[5]) << 16);
                o.w = (unsigned)f2bf(acc[6]) | ((unsigned)f2bf(acc[7]) << 16);
                ((uint4*)aggb)[(size_t)dst * 16 + ql] = o;
            }
        }
    } else {
        const float4* H4 = (const float4*)H;
        const int hl = lane & 31, half = lane >> 5;
        for (int dst = wid; dst < n_dst; dst += nwaves) {
            int b0 = beg[dst], e0 = b0 + deg[dst];
            float acc[4] = {0, 0, 0, 0};
            for (int chunk = b0; chunk < e0; chunk += 64) {
                int m = e0 - chunk; if (m > 64) m = 64;
                int idx = (lane < m) ? sorted[chunk + lane] : 0;
                for (int j = 0; j < m; j += 2) {
                    int jj = j + half;
                    int s = __shfl(idx, jj < m ? jj : m - 1);
                    float4 v = H4[(size_t)s * 32 + hl];
                    float w = (jj < m) ? 1.f : 0.f;
                    acc[0] += w * v.x; acc[1] += w * v.y;
                    acc[2] += w * v.z; acc[3] += w * v.w;
                }
            }
#pragma unroll
            for (int k = 0; k < 4; ++k) acc[k] += __shfl_xor(acc[k], 32);
            if (half == 0) {
                uint2 o;
                o.x = (unsigned)f2bf(acc[0]) | ((unsigned)f2bf(acc[1]) << 16);
                o.y = (unsigned)f2bf(acc[2]) | ((unsigned)f2bf(acc[3]) << 16);
                ((uint2*)aggb)[(size_t)dst * 32 + hl] = o;
            }
        }
    }
}

// ---------------------------------------------------------------------------
// GEMM + finalize (verified round-6 version): out = relu((aggb @ W)/max(deg,1)
// + (deg>0 ? b : 0)) via bf16 MFMA; write-once to d_out.
// ---------------------------------------------------------------------------
__global__ __launch_bounds__(256) void gemm_finalize_kernel(
    const unsigned short* __restrict__ aggb, const unsigned short* __restrict__ Wt,
    const float* __restrict__ b, const int* __restrict__ deg,
    float* __restrict__ out, int n_dst)
{
    __shared__ __align__(16) unsigned char smem[52224];
    unsigned short* Ash = (unsigned short*)smem;                   // [64][LDA]
    unsigned short* Wsh = (unsigned short*)(smem + 64 * LDA * 2);  // [128][LDA]
    float* Csh = (float*)smem;                                     // [64][132]

    const int tid  = threadIdx.x;
    const int lane = tid & 63, wv = tid >> 6;
    const size_t row0 = (size_t)blockIdx.x * 64;

#pragma unroll
    for (int t = 0; t < 4; ++t) {
        int i = tid + t * 256;
        int r = i >> 4, k8 = (i & 15) << 3;
        size_t gr = row0 + r;
        uint4 v = (gr < (size_t)n_dst) ? ((const uint4*)aggb)[gr * 16 + (i & 15)]
                                       : make_uint4(0, 0, 0, 0);
        *(uint4*)&Ash[r * LDA + k8] = v;
    }
#pragma unroll
    for (int t = 0; t < 8; ++t) {
        int i = tid + t * 256;
        int n = i >> 4, k8 = (i & 15) << 3;
        *(uint4*)&Wsh[n * LDA + k8] = ((const uint4*)Wt)[i];
    }
    __syncthreads();

    const int m0 = wv * 16;
    const int fl = lane & 15, quad = lane >> 4;

    f32x4 cacc[8];
#pragma unroll
    for (int n = 0; n < 8; ++n) cacc[n] = (f32x4){0.f, 0.f, 0.f, 0.f};

#pragma unroll
    for (int kc = 0; kc < 128; kc += 32) {
        bf16x8 a = *(const bf16x8*)&Ash[(m0 + fl) * LDA + kc + quad * 8];
#pragma unroll
        for (int n = 0; n < 8; ++n) {
            bf16x8 bf = *(const bf16x8*)&Wsh[(n * 16 + fl) * LDA + kc + quad * 8];
            cacc[n] = __builtin_amdgcn_mfma_f32_16x16x32_bf16(a, bf, cacc[n], 0, 0, 0);
        }
    }

    float inv[4], gate[4];
#pragma unroll
    for (int r = 0; r < 4; ++r) {
        size_t gr = row0 + m0 + quad * 4 + r;
        int dg = (gr < (size_t)n_dst) ? deg[gr] : 0;
        inv[r]  = 1.0f / (float)(dg > 1 ? dg : 1);
        gate[r] = (dg > 0) ? 1.0f : 0.0f;
    }
    __syncthreads();   // Ash/Wsh dead; reuse as Csh

#pragma unroll
    for (int n = 0; n < 8; ++n) {
        int col = n * 16 + fl;
        float bc = b[col];
#pragma unroll
        for (int r = 0; r < 4; ++r) {
            float v = cacc[n][r] * inv[r] + bc * gate[r];
            Csh[(m0 + quad * 4 + r) * 132 + col] = fmaxf(v, 0.0f);
        }
    }
    __syncthreads();

#pragma unroll
    for (int t = 0; t < 8; ++t) {
        int i = tid + t * 256;
        int rr = i >> 5, c4 = i & 31;
        size_t gr = row0 + rr;
        if (gr < (size_t)n_dst)
            ((float4*)out)[gr * (D / 4) + c4] = *(float4*)&Csh[rr * 132 + c4 * 4];
    }
}

extern "C" void kernel_launch(void* const* d_in, const int* in_sizes, int n_in,
                              void* d_out, int out_size, void* d_ws, size_t ws_size,
                              hipStream_t stream) {
    const float* H    = (const float*)d_in[0];   // [N_src, 128]
    const float* W    = (const float*)d_in[1];   // [128, 128]
    const float* b    = (const float*)d_in[2];   // [128]
    const int*   esrc = (const int*)d_in[3];     // [E]
    const int*   edst = (const int*)d_in[4];     // [E]
    int          E     = in_sizes[3];
    int          n_dst = out_size / D;
    const int    nsrc_elems = in_sizes[0];       // N_src * 128

    float* out = (float*)d_out;

    // ws: Wt | counts | beg | deg | total(pad) | sorted | aggb(align) | Hb(align)
    char* p = (char*)d_ws;
    unsigned short* Wt = (unsigned short*)p;  p += 128 * 128 * sizeof(unsigned short);
    int* counts = (int*)p;  p += (size_t)n_dst * 4;
    int* beg    = (int*)p;  p += (size_t)n_dst * 4;
    int* deg    = (int*)p;  p += (size_t)n_dst * 4;
    int* total  = (int*)p;  p += 256;
    int* sorted = (int*)p;  p += (size_t)E * 4;
    size_t agg_off = (((size_t)(p - (char*)d_ws)) + 255) & ~(size_t)255;
    unsigned short* aggb = (unsigned short*)((char*)d_ws + agg_off);
    size_t hb_off = (agg_off + (size_t)n_dst * D * 2 + 255) & ~(size_t)255;
    bool use_bf16h = (ws_size >= hb_off + (size_t)nsrc_elems * 2);
    unsigned* Hb = (unsigned*)((char*)d_ws + hb_off);

    int nh8 = use_bf16h ? nsrc_elems / 8 : 0;

    // Cooperative grid size: query occupancy, cap at 8 blocks/CU * 256 CUs.
    int maxblk = 8;
    if (use_bf16h)
        hipOccupancyMaxActiveBlocksPerMultiprocessor(&maxblk, mega_kernel<true>, 256, 0);
    else
        hipOccupancyMaxActiveBlocksPerMultiprocessor(&maxblk, mega_kernel<false>, 256, 0);
    if (maxblk < 1) maxblk = 1;
    if (maxblk > 8) maxblk = 8;
    int grid = maxblk * 256;

    void* kargs[] = {
        (void*)&H, (void*)&Hb, (void*)&nh8, (void*)&W, (void*)&Wt,
        (void*)&esrc, (void*)&edst, (void*)&E,
        (void*)&counts, (void*)&beg, (void*)&deg, (void*)&total,
        (void*)&sorted, (void*)&aggb, (void*)&n_dst };

    if (use_bf16h)
        hipLaunchCooperativeKernel((const void*)mega_kernel<true>,
                                   dim3(grid), dim3(256), kargs, 0, stream);
    else
        hipLaunchCooperativeKernel((const void*)mega_kernel<false>,
                                   dim3(grid), dim3(256), kargs, 0, stream);

    gemm_finalize_kernel<<<(n_dst + 63) / 64, 256, 0, stream>>>(
        aggb, Wt, b, deg, out, n_dst);
}

// Round 8
// 182.549 us; speedup vs baseline: 7.7513x; 7.7513x over previous
//
#include <hip/hip_runtime.h>

#define D 128
#define LDA 136     // bf16 elems per LDS row (+8 pad)
#define BCAP 64     // bucket capacity per dst (max degree ~32 for this data)
#define OVCAP 65536 // overflow list capacity (correct fallback, empty in practice)

typedef __attribute__((ext_vector_type(8))) short bf16x8;
typedef __attribute__((ext_vector_type(4))) float f32x4;

static __device__ __forceinline__ unsigned short f2bf(float f) {
    unsigned u = __float_as_uint(f);
    unsigned r = 0x7fffu + ((u >> 16) & 1u);   // round-to-nearest-even
    return (unsigned short)((u + r) >> 16);
}
static __device__ __forceinline__ float bflo(unsigned u) { return __uint_as_float(u << 16); }
static __device__ __forceinline__ float bfhi(unsigned u) { return __uint_as_float(u & 0xffff0000u); }

// ---------------------------------------------------------------------------
// prep: [0,nh8) H fp32->bf16 | [+16384) W transpose->bf16 | [+E) edge scatter
// into fixed-cap buckets (counts pre-zeroed by memset). Convert (BW-bound)
// and scatter (atomic-latency-bound) overlap in one dispatch.
// ---------------------------------------------------------------------------
template<bool BF16H>
__global__ __launch_bounds__(256) void prep_kernel(
    const float* __restrict__ H, unsigned* __restrict__ Hb, int nh8,
    const float* __restrict__ W, unsigned short* __restrict__ Wt,
    const int* __restrict__ esrc, const int* __restrict__ edst, int E,
    int* __restrict__ counts, int* __restrict__ buckets,
    int* __restrict__ ovcnt, int* __restrict__ ovd, int* __restrict__ ovs)
{
    int i = blockIdx.x * 256 + threadIdx.x;
    if (BF16H && i < nh8) {
        const float4* h4 = (const float4*)H;
        float4 v0 = h4[(size_t)i * 2], v1 = h4[(size_t)i * 2 + 1];
        uint4 o;
        o.x = (unsigned)f2bf(v0.x) | ((unsigned)f2bf(v0.y) << 16);
        o.y = (unsigned)f2bf(v0.z) | ((unsigned)f2bf(v0.w) << 16);
        o.z = (unsigned)f2bf(v1.x) | ((unsigned)f2bf(v1.y) << 16);
        o.w = (unsigned)f2bf(v1.z) | ((unsigned)f2bf(v1.w) << 16);
        ((uint4*)Hb)[i] = o;
        return;
    }
    int j = i - nh8;
    if (j < 16384) {                       // Wt[n][k] = bf16(W[k][n])
        int k = j >> 7, n = j & 127;
        Wt[n * 128 + k] = f2bf(W[j]);
        return;
    }
    j -= 16384;
    if (j < E) {
        int d = edst[j], s = esrc[j];
        int c = atomicAdd(&counts[d], 1);
        if (c < BCAP) {
            buckets[(size_t)d * BCAP + c] = s;
        } else {                            // correct overflow path (empty here)
            int o = atomicAdd(ovcnt, 1);
            if (o < OVCAP) { ovd[o] = d; ovs[o] = s; }
        }
    }
}

// ---------------------------------------------------------------------------
// aggregate: one wave per dst row; <=64 indices in one coalesced lane-load;
// gather 8 edges in flight (2x unroll over quad groups). bf16 out. No LDS ->
// high occupancy for latency hiding (round-5 lesson). Overflow entries
// scanned at the end (zero iterations in practice).
// ---------------------------------------------------------------------------
template<bool BF16H>
__global__ __launch_bounds__(256) void aggregate_kernel(
    const float* __restrict__ H, const uint4* __restrict__ Hb,
    const int* __restrict__ buckets, const int* __restrict__ counts,
    const int* __restrict__ ovcnt, const int* __restrict__ ovd,
    const int* __restrict__ ovs, unsigned short* __restrict__ aggb, int n_dst)
{
    int dst = blockIdx.x * 4 + (threadIdx.x >> 6);
    if (dst >= n_dst) return;
    int lane = threadIdx.x & 63;
    int dg = counts[dst];
    int m = dg < BCAP ? dg : BCAP;
    int nov = *ovcnt; if (nov > OVCAP) nov = OVCAP;
    int idx = (lane < m) ? buckets[(size_t)dst * BCAP + lane] : 0;

    if (BF16H) {
        const int ql = lane & 15, quad = lane >> 4;
        float acc[8] = {0, 0, 0, 0, 0, 0, 0, 0};
        int j = 0;
        for (; j + 8 <= m; j += 8) {                 // 8 edges in flight
            int sA = __shfl(idx, j + quad);
            int sB = __shfl(idx, j + 4 + quad);
            uint4 ha = Hb[(size_t)sA * 16 + ql];
            uint4 hb = Hb[(size_t)sB * 16 + ql];
            acc[0] += bflo(ha.x) + bflo(hb.x); acc[1] += bfhi(ha.x) + bfhi(hb.x);
            acc[2] += bflo(ha.y) + bflo(hb.y); acc[3] += bfhi(ha.y) + bfhi(hb.y);
            acc[4] += bflo(ha.z) + bflo(hb.z); acc[5] += bfhi(ha.z) + bfhi(hb.z);
            acc[6] += bflo(ha.w) + bflo(hb.w); acc[7] += bfhi(ha.w) + bfhi(hb.w);
        }
        for (; j < m; j += 4) {                      // predicated tail
            int jj = j + quad;
            int s = __shfl(idx, jj < m ? jj : m - 1);
            uint4 hv = Hb[(size_t)s * 16 + ql];
            float w = (jj < m) ? 1.f : 0.f;
            acc[0] += w * bflo(hv.x); acc[1] += w * bfhi(hv.x);
            acc[2] += w * bflo(hv.y); acc[3] += w * bfhi(hv.y);
            acc[4] += w * bflo(hv.z); acc[5] += w * bfhi(hv.z);
            acc[6] += w * bflo(hv.w); acc[7] += w * bfhi(hv.w);
        }
        for (int k = quad; k < nov; k += 4) {        // overflow (empty normally)
            if (ovd[k] == dst) {
                uint4 hv = Hb[(size_t)ovs[k] * 16 + ql];
                acc[0] += bflo(hv.x); acc[1] += bfhi(hv.x);
                acc[2] += bflo(hv.y); acc[3] += bfhi(hv.y);
                acc[4] += bflo(hv.z); acc[5] += bfhi(hv.z);
                acc[6] += bflo(hv.w); acc[7] += bfhi(hv.w);
            }
        }
#pragma unroll
        for (int k = 0; k < 8; ++k) {
            acc[k] += __shfl_xor(acc[k], 16);
            acc[k] += __shfl_xor(acc[k], 32);
        }
        if (quad == 0) {
            uint4 o;
            o.x = (unsigned)f2bf(acc[0]) | ((unsigned)f2bf(acc[1]) << 16);
            o.y = (unsigned)f2bf(acc[2]) | ((unsigned)f2bf(acc[3]) << 16);
            o.z = (unsigned)f2bf(acc[4]) | ((unsigned)f2bf(acc[5]) << 16);
            o.w = (unsigned)f2bf(acc[6]) | ((unsigned)f2bf(acc[7]) << 16);
            ((uint4*)aggb)[(size_t)dst * 16 + ql] = o;
        }
    } else {
        const int hl = lane & 31, half = lane >> 5;
        const float4* H4 = (const float4*)H;
        float acc[4] = {0, 0, 0, 0};
        int j = 0;
        for (; j + 4 <= m; j += 4) {
            int sA = __shfl(idx, j + half);
            int sB = __shfl(idx, j + 2 + half);
            float4 va = H4[(size_t)sA * 32 + hl];
            float4 vb = H4[(size_t)sB * 32 + hl];
            acc[0] += va.x + vb.x; acc[1] += va.y + vb.y;
            acc[2] += va.z + vb.z; acc[3] += va.w + vb.w;
        }
        for (; j < m; j += 2) {
            int jj = j + half;
            int s = __shfl(idx, jj < m ? jj : m - 1);
            float4 v = H4[(size_t)s * 32 + hl];
            float w = (jj < m) ? 1.f : 0.f;
            acc[0] += w * v.x; acc[1] += w * v.y;
            acc[2] += w * v.z; acc[3] += w * v.w;
        }
        for (int k = half; k < nov; k += 2) {
            if (ovd[k] == dst) {
                float4 v = H4[(size_t)ovs[k] * 32 + hl];
                acc[0] += v.x; acc[1] += v.y; acc[2] += v.z; acc[3] += v.w;
            }
        }
#pragma unroll
        for (int k = 0; k < 4; ++k) acc[k] += __shfl_xor(acc[k], 32);
        if (half == 0) {
            uint2 o;
            o.x = (unsigned)f2bf(acc[0]) | ((unsigned)f2bf(acc[1]) << 16);
            o.y = (unsigned)f2bf(acc[2]) | ((unsigned)f2bf(acc[3]) << 16);
            ((uint2*)aggb)[(size_t)dst * 32 + hl] = o;
        }
    }
}

// ---------------------------------------------------------------------------
// GEMM + finalize (verified): out = relu((aggb @ W)/max(deg,1) +
// (deg>0 ? b : 0)) via bf16 MFMA; write-once to d_out.
// ---------------------------------------------------------------------------
__global__ __launch_bounds__(256) void gemm_finalize_kernel(
    const unsigned short* __restrict__ aggb, const unsigned short* __restrict__ Wt,
    const float* __restrict__ b, const int* __restrict__ deg,
    float* __restrict__ out, int n_dst)
{
    __shared__ __align__(16) unsigned char smem[52224];
    unsigned short* Ash = (unsigned short*)smem;                   // [64][LDA]
    unsigned short* Wsh = (unsigned short*)(smem + 64 * LDA * 2);  // [128][LDA]
    float* Csh = (float*)smem;                                     // [64][132]

    const int tid  = threadIdx.x;
    const int lane = tid & 63, wv = tid >> 6;
    const size_t row0 = (size_t)blockIdx.x * 64;

#pragma unroll
    for (int t = 0; t < 4; ++t) {
        int i = tid + t * 256;
        int r = i >> 4, k8 = (i & 15) << 3;
        size_t gr = row0 + r;
        uint4 v = (gr < (size_t)n_dst) ? ((const uint4*)aggb)[gr * 16 + (i & 15)]
                                       : make_uint4(0, 0, 0, 0);
        *(uint4*)&Ash[r * LDA + k8] = v;
    }
#pragma unroll
    for (int t = 0; t < 8; ++t) {
        int i = tid + t * 256;
        int n = i >> 4, k8 = (i & 15) << 3;
        *(uint4*)&Wsh[n * LDA + k8] = ((const uint4*)Wt)[i];
    }
    __syncthreads();

    const int m0 = wv * 16;
    const int fl = lane & 15, quad = lane >> 4;

    f32x4 cacc[8];
#pragma unroll
    for (int n = 0; n < 8; ++n) cacc[n] = (f32x4){0.f, 0.f, 0.f, 0.f};

#pragma unroll
    for (int kc = 0; kc < 128; kc += 32) {
        bf16x8 a = *(const bf16x8*)&Ash[(m0 + fl) * LDA + kc + quad * 8];
#pragma unroll
        for (int n = 0; n < 8; ++n) {
            bf16x8 bf = *(const bf16x8*)&Wsh[(n * 16 + fl) * LDA + kc + quad * 8];
            cacc[n] = __builtin_amdgcn_mfma_f32_16x16x32_bf16(a, bf, cacc[n], 0, 0, 0);
        }
    }

    float inv[4], gate[4];
#pragma unroll
    for (int r = 0; r < 4; ++r) {
        size_t gr = row0 + m0 + quad * 4 + r;
        int dg = (gr < (size_t)n_dst) ? deg[gr] : 0;
        inv[r]  = 1.0f / (float)(dg > 1 ? dg : 1);
        gate[r] = (dg > 0) ? 1.0f : 0.0f;
    }
    __syncthreads();   // Ash/Wsh dead; reuse as Csh

#pragma unroll
    for (int n = 0; n < 8; ++n) {
        int col = n * 16 + fl;
        float bc = b[col];
#pragma unroll
        for (int r = 0; r < 4; ++r) {
            float v = cacc[n][r] * inv[r] + bc * gate[r];
            Csh[(m0 + quad * 4 + r) * 132 + col] = fmaxf(v, 0.0f);
        }
    }
    __syncthreads();

#pragma unroll
    for (int t = 0; t < 8; ++t) {
        int i = tid + t * 256;
        int rr = i >> 5, c4 = i & 31;
        size_t gr = row0 + rr;
        if (gr < (size_t)n_dst)
            ((float4*)out)[gr * (D / 4) + c4] = *(float4*)&Csh[rr * 132 + c4 * 4];
    }
}

extern "C" void kernel_launch(void* const* d_in, const int* in_sizes, int n_in,
                              void* d_out, int out_size, void* d_ws, size_t ws_size,
                              hipStream_t stream) {
    const float* H    = (const float*)d_in[0];   // [N_src, 128]
    const float* W    = (const float*)d_in[1];   // [128, 128]
    const float* b    = (const float*)d_in[2];   // [128]
    const int*   esrc = (const int*)d_in[3];     // [E]
    const int*   edst = (const int*)d_in[4];     // [E]
    const int    E     = in_sizes[3];
    const int    n_dst = out_size / D;
    const int    nsrc_elems = in_sizes[0];       // N_src * 128

    float* out = (float*)d_out;

    // ws: Wt | counts | ovcnt(pad) | ovd | ovs | buckets | aggb | Hb
    char* p = (char*)d_ws;
    unsigned short* Wt = (unsigned short*)p;  p += 128 * 128 * sizeof(unsigned short);
    int* counts = (int*)p;  p += (size_t)n_dst * 4;
    int* ovcnt  = (int*)p;  p += 256;            // zeroed together with counts
    int* ovd    = (int*)p;  p += (size_t)OVCAP * 4;
    int* ovs    = (int*)p;  p += (size_t)OVCAP * 4;
    int* buckets= (int*)p;  p += (size_t)n_dst * BCAP * 4;
    size_t agg_off = (((size_t)(p - (char*)d_ws)) + 255) & ~(size_t)255;
    unsigned short* aggb = (unsigned short*)((char*)d_ws + agg_off);
    size_t hb_off = (agg_off + (size_t)n_dst * D * 2 + 255) & ~(size_t)255;
    bool use_bf16h = (ws_size >= hb_off + (size_t)nsrc_elems * 2);
    unsigned* Hb = (unsigned*)((char*)d_ws + hb_off);

    const int nh8 = use_bf16h ? nsrc_elems / 8 : 0;
    const int prep_work = nh8 + 16384 + E;

    // Zero counts + overflow cursor in one memset (contiguous).
    hipMemsetAsync(counts, 0, (size_t)n_dst * 4 + 256, stream);

    if (use_bf16h) {
        prep_kernel<true><<<(prep_work + 255) / 256, 256, 0, stream>>>(
            H, Hb, nh8, W, Wt, esrc, edst, E, counts, buckets, ovcnt, ovd, ovs);
        aggregate_kernel<true><<<(n_dst + 3) / 4, 256, 0, stream>>>(
            H, (const uint4*)Hb, buckets, counts, ovcnt, ovd, ovs, aggb, n_dst);
    } else {
        prep_kernel<false><<<(prep_work + 255) / 256, 256, 0, stream>>>(
            H, Hb, nh8, W, Wt, esrc, edst, E, counts, buckets, ovcnt, ovd, ovs);
        aggregate_kernel<false><<<(n_dst + 3) / 4, 256, 0, stream>>>(
            H, nullptr, buckets, counts, ovcnt, ovd, ovs, aggb, n_dst);
    }

    gemm_finalize_kernel<<<(n_dst + 63) / 64, 256, 0, stream>>>(
        aggb, Wt, b, counts, out, n_dst);
}

// Round 9
// 174.247 us; speedup vs baseline: 8.1207x; 1.0476x over previous
//
#include <hip/hip_runtime.h>

#define D 128
#define LDA 136     // bf16 elems per LDS row (+8 pad)
#define BCAP 64     // bucket capacity per dst (max degree ~35 for this data)
#define CSTRIDE 16  // counts padded: 1 counter per 64B line (kills same-line atomic serialization)
#define OVCAP 65536 // overflow list capacity (correct fallback, empty in practice)

typedef __attribute__((ext_vector_type(8))) short bf16x8;
typedef __attribute__((ext_vector_type(4))) float f32x4;

static __device__ __forceinline__ unsigned short f2bf(float f) {
    unsigned u = __float_as_uint(f);
    unsigned r = 0x7fffu + ((u >> 16) & 1u);   // round-to-nearest-even
    return (unsigned short)((u + r) >> 16);
}
static __device__ __forceinline__ float bflo(unsigned u) { return __uint_as_float(u << 16); }
static __device__ __forceinline__ float bfhi(unsigned u) { return __uint_as_float(u & 0xffff0000u); }

// ---------------------------------------------------------------------------
// prep: threads [0,eth) scatter 4 edges each (FIRST, so the latency-bound
// scatter overlaps the BW-bound convert instead of trailing it; 4 independent
// atomic chains in flight per thread); [eth,+nh8) H fp32->bf16; [+16384) W
// transpose->bf16. counts padded to 1/line.
// ---------------------------------------------------------------------------
template<bool BF16H>
__global__ __launch_bounds__(256) void prep_kernel(
    const float* __restrict__ H, unsigned* __restrict__ Hb, int nh8,
    const float* __restrict__ W, unsigned short* __restrict__ Wt,
    const int* __restrict__ esrc, const int* __restrict__ edst, int E, int eth,
    int* __restrict__ counts, int* __restrict__ buckets,
    int* __restrict__ ovcnt, int* __restrict__ ovd, int* __restrict__ ovs)
{
    int i = blockIdx.x * 256 + threadIdx.x;
    if (i < eth) {
        int d[4], s[4], c[4];
        bool v[4];
#pragma unroll
        for (int k = 0; k < 4; ++k) {            // load phase (coalesced groups)
            int e = i + k * eth;
            v[k] = e < E;
            d[k] = v[k] ? edst[e] : 0;
            s[k] = v[k] ? esrc[e] : 0;
        }
#pragma unroll
        for (int k = 0; k < 4; ++k)              // 4 atomics in flight
            if (v[k]) c[k] = atomicAdd(&counts[(size_t)d[k] * CSTRIDE], 1);
#pragma unroll
        for (int k = 0; k < 4; ++k) {            // store phase
            if (v[k]) {
                if (c[k] < BCAP) {
                    buckets[(size_t)d[k] * BCAP + c[k]] = s[k];
                } else {                          // correct overflow path (empty here)
                    int o = atomicAdd(ovcnt, 1);
                    if (o < OVCAP) { ovd[o] = d[k]; ovs[o] = s[k]; }
                }
            }
        }
        return;
    }
    int j = i - eth;
    if (BF16H && j < nh8) {
        const float4* h4 = (const float4*)H;
        float4 v0 = h4[(size_t)j * 2], v1 = h4[(size_t)j * 2 + 1];
        uint4 o;
        o.x = (unsigned)f2bf(v0.x) | ((unsigned)f2bf(v0.y) << 16);
        o.y = (unsigned)f2bf(v0.z) | ((unsigned)f2bf(v0.w) << 16);
        o.z = (unsigned)f2bf(v1.x) | ((unsigned)f2bf(v1.y) << 16);
        o.w = (unsigned)f2bf(v1.z) | ((unsigned)f2bf(v1.w) << 16);
        ((uint4*)Hb)[j] = o;
        return;
    }
    j -= nh8;
    if (j < 16384) {                       // Wt[n][k] = bf16(W[k][n])
        int k = j >> 7, n = j & 127;
        Wt[n * 128 + k] = f2bf(W[j]);
    }
}

// ---------------------------------------------------------------------------
// aggregate: one wave per dst row; <=64 indices in one coalesced lane-load;
// gather 8 edges in flight. bf16 out. No LDS -> high occupancy (round-5
// lesson). Overflow entries scanned at the end (zero iters in practice).
// ---------------------------------------------------------------------------
template<bool BF16H>
__global__ __launch_bounds__(256) void aggregate_kernel(
    const float* __restrict__ H, const uint4* __restrict__ Hb,
    const int* __restrict__ buckets, const int* __restrict__ counts,
    const int* __restrict__ ovcnt, const int* __restrict__ ovd,
    const int* __restrict__ ovs, unsigned short* __restrict__ aggb, int n_dst)
{
    int dst = blockIdx.x * 4 + (threadIdx.x >> 6);
    if (dst >= n_dst) return;
    int lane = threadIdx.x & 63;
    int dg = counts[(size_t)dst * CSTRIDE];
    int m = dg < BCAP ? dg : BCAP;
    int nov = *ovcnt; if (nov > OVCAP) nov = OVCAP;
    int idx = (lane < m) ? buckets[(size_t)dst * BCAP + lane] : 0;

    if (BF16H) {
        const int ql = lane & 15, quad = lane >> 4;
        float acc[8] = {0, 0, 0, 0, 0, 0, 0, 0};
        int j = 0;
        for (; j + 8 <= m; j += 8) {                 // 8 edges in flight
            int sA = __shfl(idx, j + quad);
            int sB = __shfl(idx, j + 4 + quad);
            uint4 ha = Hb[(size_t)sA * 16 + ql];
            uint4 hb = Hb[(size_t)sB * 16 + ql];
            acc[0] += bflo(ha.x) + bflo(hb.x); acc[1] += bfhi(ha.x) + bfhi(hb.x);
            acc[2] += bflo(ha.y) + bflo(hb.y); acc[3] += bfhi(ha.y) + bfhi(hb.y);
            acc[4] += bflo(ha.z) + bflo(hb.z); acc[5] += bfhi(ha.z) + bfhi(hb.z);
            acc[6] += bflo(ha.w) + bflo(hb.w); acc[7] += bfhi(ha.w) + bfhi(hb.w);
        }
        for (; j < m; j += 4) {                      // predicated tail
            int jj = j + quad;
            int s = __shfl(idx, jj < m ? jj : m - 1);
            uint4 hv = Hb[(size_t)s * 16 + ql];
            float w = (jj < m) ? 1.f : 0.f;
            acc[0] += w * bflo(hv.x); acc[1] += w * bfhi(hv.x);
            acc[2] += w * bflo(hv.y); acc[3] += w * bfhi(hv.y);
            acc[4] += w * bflo(hv.z); acc[5] += w * bfhi(hv.z);
            acc[6] += w * bflo(hv.w); acc[7] += w * bfhi(hv.w);
        }
        for (int k = quad; k < nov; k += 4) {        // overflow (empty normally)
            if (ovd[k] == dst) {
                uint4 hv = Hb[(size_t)ovs[k] * 16 + ql];
                acc[0] += bflo(hv.x); acc[1] += bfhi(hv.x);
                acc[2] += bflo(hv.y); acc[3] += bfhi(hv.y);
                acc[4] += bflo(hv.z); acc[5] += bfhi(hv.z);
                acc[6] += bflo(hv.w); acc[7] += bfhi(hv.w);
            }
        }
#pragma unroll
        for (int k = 0; k < 8; ++k) {
            acc[k] += __shfl_xor(acc[k], 16);
            acc[k] += __shfl_xor(acc[k], 32);
        }
        if (quad == 0) {
            uint4 o;
            o.x = (unsigned)f2bf(acc[0]) | ((unsigned)f2bf(acc[1]) << 16);
            o.y = (unsigned)f2bf(acc[2]) | ((unsigned)f2bf(acc[3]) << 16);
            o.z = (unsigned)f2bf(acc[4]) | ((unsigned)f2bf(acc[5]) << 16);
            o.w = (unsigned)f2bf(acc[6]) | ((unsigned)f2bf(acc[7]) << 16);
            ((uint4*)aggb)[(size_t)dst * 16 + ql] = o;
        }
    } else {
        const int hl = lane & 31, half = lane >> 5;
        const float4* H4 = (const float4*)H;
        float acc[4] = {0, 0, 0, 0};
        int j = 0;
        for (; j + 4 <= m; j += 4) {
            int sA = __shfl(idx, j + half);
            int sB = __shfl(idx, j + 2 + half);
            float4 va = H4[(size_t)sA * 32 + hl];
            float4 vb = H4[(size_t)sB * 32 + hl];
            acc[0] += va.x + vb.x; acc[1] += va.y + vb.y;
            acc[2] += va.z + vb.z; acc[3] += va.w + vb.w;
        }
        for (; j < m; j += 2) {
            int jj = j + half;
            int s = __shfl(idx, jj < m ? jj : m - 1);
            float4 v = H4[(size_t)s * 32 + hl];
            float w = (jj < m) ? 1.f : 0.f;
            acc[0] += w * v.x; acc[1] += w * v.y;
            acc[2] += w * v.z; acc[3] += w * v.w;
        }
        for (int k = half; k < nov; k += 2) {
            if (ovd[k] == dst) {
                float4 v = H4[(size_t)ovs[k] * 32 + hl];
                acc[0] += v.x; acc[1] += v.y; acc[2] += v.z; acc[3] += v.w;
            }
        }
#pragma unroll
        for (int k = 0; k < 4; ++k) acc[k] += __shfl_xor(acc[k], 32);
        if (half == 0) {
            uint2 o;
            o.x = (unsigned)f2bf(acc[0]) | ((unsigned)f2bf(acc[1]) << 16);
            o.y = (unsigned)f2bf(acc[2]) | ((unsigned)f2bf(acc[3]) << 16);
            ((uint2*)aggb)[(size_t)dst * 32 + hl] = o;
        }
    }
}

// ---------------------------------------------------------------------------
// GEMM + finalize (verified): out = relu((aggb @ W)/max(deg,1) +
// (deg>0 ? b : 0)) via bf16 MFMA; write-once to d_out.
// ---------------------------------------------------------------------------
__global__ __launch_bounds__(256) void gemm_finalize_kernel(
    const unsigned short* __restrict__ aggb, const unsigned short* __restrict__ Wt,
    const float* __restrict__ b, const int* __restrict__ counts,
    float* __restrict__ out, int n_dst)
{
    __shared__ __align__(16) unsigned char smem[52224];
    unsigned short* Ash = (unsigned short*)smem;                   // [64][LDA]
    unsigned short* Wsh = (unsigned short*)(smem + 64 * LDA * 2);  // [128][LDA]
    float* Csh = (float*)smem;                                     // [64][132]

    const int tid  = threadIdx.x;
    const int lane = tid & 63, wv = tid >> 6;
    const size_t row0 = (size_t)blockIdx.x * 64;

#pragma unroll
    for (int t = 0; t < 4; ++t) {
        int i = tid + t * 256;
        int r = i >> 4, k8 = (i & 15) << 3;
        size_t gr = row0 + r;
        uint4 v = (gr < (size_t)n_dst) ? ((const uint4*)aggb)[gr * 16 + (i & 15)]
                                       : make_uint4(0, 0, 0, 0);
        *(uint4*)&Ash[r * LDA + k8] = v;
    }
#pragma unroll
    for (int t = 0; t < 8; ++t) {
        int i = tid + t * 256;
        int n = i >> 4, k8 = (i & 15) << 3;
        *(uint4*)&Wsh[n * LDA + k8] = ((const uint4*)Wt)[i];
    }
    __syncthreads();

    const int m0 = wv * 16;
    const int fl = lane & 15, quad = lane >> 4;

    f32x4 cacc[8];
#pragma unroll
    for (int n = 0; n < 8; ++n) cacc[n] = (f32x4){0.f, 0.f, 0.f, 0.f};

#pragma unroll
    for (int kc = 0; kc < 128; kc += 32) {
        bf16x8 a = *(const bf16x8*)&Ash[(m0 + fl) * LDA + kc + quad * 8];
#pragma unroll
        for (int n = 0; n < 8; ++n) {
            bf16x8 bf = *(const bf16x8*)&Wsh[(n * 16 + fl) * LDA + kc + quad * 8];
            cacc[n] = __builtin_amdgcn_mfma_f32_16x16x32_bf16(a, bf, cacc[n], 0, 0, 0);
        }
    }

    float inv[4], gate[4];
#pragma unroll
    for (int r = 0; r < 4; ++r) {
        size_t gr = row0 + m0 + quad * 4 + r;
        int dg = (gr < (size_t)n_dst) ? counts[gr * CSTRIDE] : 0;
        inv[r]  = 1.0f / (float)(dg > 1 ? dg : 1);
        gate[r] = (dg > 0) ? 1.0f : 0.0f;
    }
    __syncthreads();   // Ash/Wsh dead; reuse as Csh

#pragma unroll
    for (int n = 0; n < 8; ++n) {
        int col = n * 16 + fl;
        float bc = b[col];
#pragma unroll
        for (int r = 0; r < 4; ++r) {
            float v = cacc[n][r] * inv[r] + bc * gate[r];
            Csh[(m0 + quad * 4 + r) * 132 + col] = fmaxf(v, 0.0f);
        }
    }
    __syncthreads();

#pragma unroll
    for (int t = 0; t < 8; ++t) {
        int i = tid + t * 256;
        int rr = i >> 5, c4 = i & 31;
        size_t gr = row0 + rr;
        if (gr < (size_t)n_dst)
            ((float4*)out)[gr * (D / 4) + c4] = *(float4*)&Csh[rr * 132 + c4 * 4];
    }
}

extern "C" void kernel_launch(void* const* d_in, const int* in_sizes, int n_in,
                              void* d_out, int out_size, void* d_ws, size_t ws_size,
                              hipStream_t stream) {
    const float* H    = (const float*)d_in[0];   // [N_src, 128]
    const float* W    = (const float*)d_in[1];   // [128, 128]
    const float* b    = (const float*)d_in[2];   // [128]
    const int*   esrc = (const int*)d_in[3];     // [E]
    const int*   edst = (const int*)d_in[4];     // [E]
    const int    E     = in_sizes[3];
    const int    n_dst = out_size / D;
    const int    nsrc_elems = in_sizes[0];       // N_src * 128

    float* out = (float*)d_out;

    // ws: Wt | counts(padded) | ovcnt(pad) | ovd | ovs | buckets | aggb | Hb
    char* p = (char*)d_ws;
    unsigned short* Wt = (unsigned short*)p;  p += 128 * 128 * sizeof(unsigned short);
    int* counts = (int*)p;  p += (size_t)n_dst * CSTRIDE * 4;
    int* ovcnt  = (int*)p;  p += 256;            // zeroed together with counts
    int* ovd    = (int*)p;  p += (size_t)OVCAP * 4;
    int* ovs    = (int*)p;  p += (size_t)OVCAP * 4;
    int* buckets= (int*)p;  p += (size_t)n_dst * BCAP * 4;
    size_t agg_off = (((size_t)(p - (char*)d_ws)) + 255) & ~(size_t)255;
    unsigned short* aggb = (unsigned short*)((char*)d_ws + agg_off);
    size_t hb_off = (agg_off + (size_t)n_dst * D * 2 + 255) & ~(size_t)255;
    bool use_bf16h = (ws_size >= hb_off + (size_t)nsrc_elems * 2);
    unsigned* Hb = (unsigned*)((char*)d_ws + hb_off);

    const int nh8 = use_bf16h ? nsrc_elems / 8 : 0;
    const int eth = (E + 3) / 4;                 // 4 edges per thread
    const int prep_work = eth + nh8 + 16384;

    // Zero padded counts + overflow cursor in one memset (contiguous, ~3.2MB).
    hipMemsetAsync(counts, 0, (size_t)n_dst * CSTRIDE * 4 + 256, stream);

    if (use_bf16h) {
        prep_kernel<true><<<(prep_work + 255) / 256, 256, 0, stream>>>(
            H, Hb, nh8, W, Wt, esrc, edst, E, eth, counts, buckets, ovcnt, ovd, ovs);
        aggregate_kernel<true><<<(n_dst + 3) / 4, 256, 0, stream>>>(
            H, (const uint4*)Hb, buckets, counts, ovcnt, ovd, ovs, aggb, n_dst);
    } else {
        prep_kernel<false><<<(prep_work + 255) / 256, 256, 0, stream>>>(
            H, Hb, nh8, W, Wt, esrc, edst, E, eth, counts, buckets, ovcnt, ovd, ovs);
        aggregate_kernel<false><<<(n_dst + 3) / 4, 256, 0, stream>>>(
            H, nullptr, buckets, counts, ovcnt, ovd, ovs, aggb, n_dst);
    }

    gemm_finalize_kernel<<<(n_dst + 63) / 64, 256, 0, stream>>>(
        aggb, Wt, b, counts, out, n_dst);
}

// Round 10
// 163.664 us; speedup vs baseline: 8.6458x; 1.0647x over previous
//
#include <hip/hip_runtime.h>

#define D 128
#define LDA 136     // bf16 elems per LDS row (+8 pad)
#define BCAP 64     // bucket capacity per dst (max degree ~35 for this data)
#define CSTRIDE 16  // counts padded: 1 counter per 64B line
#define OVCAP 65536 // overflow list capacity (correct fallback, empty in practice)

typedef __attribute__((ext_vector_type(8))) short bf16x8;
typedef __attribute__((ext_vector_type(4))) float f32x4;

static __device__ __forceinline__ unsigned short f2bf(float f) {
    unsigned u = __float_as_uint(f);
    unsigned r = 0x7fffu + ((u >> 16) & 1u);   // round-to-nearest-even
    return (unsigned short)((u + r) >> 16);
}
static __device__ __forceinline__ float bflo(unsigned u) { return __uint_as_float(u << 16); }
static __device__ __forceinline__ float bfhi(unsigned u) { return __uint_as_float(u & 0xffff0000u); }

// ---------------------------------------------------------------------------
// prep: thread i handles edge i (if i<E) INTERLEAVED with convert chunk i.
// Issue order: edge loads -> atomic -> convert loads -> convert store ->
// bucket store. The atomic return rides in the vmcnt queue ahead of the
// convert loads, so its latency is hidden behind the convert's own wait —
// and all 600K atomics are spread across the full convert grid's waves
// (round-9 lesson: a narrow edge-only thread range can't cover atomic
// latency with TLP).
// ---------------------------------------------------------------------------
template<bool BF16H>
__global__ __launch_bounds__(256) void prep_kernel(
    const float* __restrict__ H, unsigned* __restrict__ Hb, int nh8,
    const float* __restrict__ W, unsigned short* __restrict__ Wt,
    const int* __restrict__ esrc, const int* __restrict__ edst, int E,
    int* __restrict__ counts, int* __restrict__ buckets,
    int* __restrict__ ovcnt, int* __restrict__ ovd, int* __restrict__ ovs)
{
    int i = blockIdx.x * 256 + threadIdx.x;

    // --- edge: load + atomic issued first ---
    int d = 0, s = 0, c = 0;
    bool hasE = (i < E);
    if (hasE) { d = edst[i]; s = esrc[i]; }
    if (hasE) c = atomicAdd(&counts[(size_t)d * CSTRIDE], 1);

    // --- convert (independent; its loads queue behind the atomic) ---
    if (BF16H && i < nh8) {
        const float4* h4 = (const float4*)H;
        float4 v0 = h4[(size_t)i * 2], v1 = h4[(size_t)i * 2 + 1];
        uint4 o;
        o.x = (unsigned)f2bf(v0.x) | ((unsigned)f2bf(v0.y) << 16);
        o.y = (unsigned)f2bf(v0.z) | ((unsigned)f2bf(v0.w) << 16);
        o.z = (unsigned)f2bf(v1.x) | ((unsigned)f2bf(v1.y) << 16);
        o.w = (unsigned)f2bf(v1.z) | ((unsigned)f2bf(v1.w) << 16);
        ((uint4*)Hb)[i] = o;
    } else {
        int j = i - nh8;
        if (j >= 0 && j < 16384) {         // Wt[n][k] = bf16(W[k][n])
            int k = j >> 7, n = j & 127;
            Wt[n * 128 + k] = f2bf(W[j]);
        }
    }

    // --- edge: place into bucket (atomic result long since landed) ---
    if (hasE) {
        if (c < BCAP) {
            buckets[(size_t)d * BCAP + c] = s;
        } else {                            // correct overflow path (empty here)
            int o = atomicAdd(ovcnt, 1);
            if (o < OVCAP) { ovd[o] = d; ovs[o] = s; }
        }
    }
}

// ---------------------------------------------------------------------------
// aggregate: one wave per dst row; <=64 indices in one coalesced lane-load;
// gather 8 edges in flight. bf16 out. No LDS -> high occupancy (round-5
// lesson). Overflow entries scanned at the end (zero iters in practice).
// ---------------------------------------------------------------------------
template<bool BF16H>
__global__ __launch_bounds__(256) void aggregate_kernel(
    const float* __restrict__ H, const uint4* __restrict__ Hb,
    const int* __restrict__ buckets, const int* __restrict__ counts,
    const int* __restrict__ ovcnt, const int* __restrict__ ovd,
    const int* __restrict__ ovs, unsigned short* __restrict__ aggb, int n_dst)
{
    int dst = blockIdx.x * 4 + (threadIdx.x >> 6);
    if (dst >= n_dst) return;
    int lane = threadIdx.x & 63;
    int dg = counts[(size_t)dst * CSTRIDE];
    int m = dg < BCAP ? dg : BCAP;
    int nov = *ovcnt; if (nov > OVCAP) nov = OVCAP;
    int idx = (lane < m) ? buckets[(size_t)dst * BCAP + lane] : 0;

    if (BF16H) {
        const int ql = lane & 15, quad = lane >> 4;
        float acc[8] = {0, 0, 0, 0, 0, 0, 0, 0};
        int j = 0;
        for (; j + 8 <= m; j += 8) {                 // 8 edges in flight
            int sA = __shfl(idx, j + quad);
            int sB = __shfl(idx, j + 4 + quad);
            uint4 ha = Hb[(size_t)sA * 16 + ql];
            uint4 hb = Hb[(size_t)sB * 16 + ql];
            acc[0] += bflo(ha.x) + bflo(hb.x); acc[1] += bfhi(ha.x) + bfhi(hb.x);
            acc[2] += bflo(ha.y) + bflo(hb.y); acc[3] += bfhi(ha.y) + bfhi(hb.y);
            acc[4] += bflo(ha.z) + bflo(hb.z); acc[5] += bfhi(ha.z) + bfhi(hb.z);
            acc[6] += bflo(ha.w) + bflo(hb.w); acc[7] += bfhi(ha.w) + bfhi(hb.w);
        }
        for (; j < m; j += 4) {                      // predicated tail
            int jj = j + quad;
            int s = __shfl(idx, jj < m ? jj : m - 1);
            uint4 hv = Hb[(size_t)s * 16 + ql];
            float w = (jj < m) ? 1.f : 0.f;
            acc[0] += w * bflo(hv.x); acc[1] += w * bfhi(hv.x);
            acc[2] += w * bflo(hv.y); acc[3] += w * bfhi(hv.y);
            acc[4] += w * bflo(hv.z); acc[5] += w * bfhi(hv.z);
            acc[6] += w * bflo(hv.w); acc[7] += w * bfhi(hv.w);
        }
        for (int k = quad; k < nov; k += 4) {        // overflow (empty normally)
            if (ovd[k] == dst) {
                uint4 hv = Hb[(size_t)ovs[k] * 16 + ql];
                acc[0] += bflo(hv.x); acc[1] += bfhi(hv.x);
                acc[2] += bflo(hv.y); acc[3] += bfhi(hv.y);
                acc[4] += bflo(hv.z); acc[5] += bfhi(hv.z);
                acc[6] += bflo(hv.w); acc[7] += bfhi(hv.w);
            }
        }
#pragma unroll
        for (int k = 0; k < 8; ++k) {
            acc[k] += __shfl_xor(acc[k], 16);
            acc[k] += __shfl_xor(acc[k], 32);
        }
        if (quad == 0) {
            uint4 o;
            o.x = (unsigned)f2bf(acc[0]) | ((unsigned)f2bf(acc[1]) << 16);
            o.y = (unsigned)f2bf(acc[2]) | ((unsigned)f2bf(acc[3]) << 16);
            o.z = (unsigned)f2bf(acc[4]) | ((unsigned)f2bf(acc[5]) << 16);
            o.w = (unsigned)f2bf(acc[6]) | ((unsigned)f2bf(acc[7]) << 16);
            ((uint4*)aggb)[(size_t)dst * 16 + ql] = o;
        }
    } else {
        const int hl = lane & 31, half = lane >> 5;
        const float4* H4 = (const float4*)H;
        float acc[4] = {0, 0, 0, 0};
        int j = 0;
        for (; j + 4 <= m; j += 4) {
            int sA = __shfl(idx, j + half);
            int sB = __shfl(idx, j + 2 + half);
            float4 va = H4[(size_t)sA * 32 + hl];
            float4 vb = H4[(size_t)sB * 32 + hl];
            acc[0] += va.x + vb.x; acc[1] += va.y + vb.y;
            acc[2] += va.z + vb.z; acc[3] += va.w + vb.w;
        }
        for (; j < m; j += 2) {
            int jj = j + half;
            int s = __shfl(idx, jj < m ? jj : m - 1);
            float4 v = H4[(size_t)s * 32 + hl];
            float w = (jj < m) ? 1.f : 0.f;
            acc[0] += w * v.x; acc[1] += w * v.y;
            acc[2] += w * v.z; acc[3] += w * v.w;
        }
        for (int k = half; k < nov; k += 2) {
            if (ovd[k] == dst) {
                float4 v = H4[(size_t)ovs[k] * 32 + hl];
                acc[0] += v.x; acc[1] += v.y; acc[2] += v.z; acc[3] += v.w;
            }
        }
#pragma unroll
        for (int k = 0; k < 4; ++k) acc[k] += __shfl_xor(acc[k], 32);
        if (half == 0) {
            uint2 o;
            o.x = (unsigned)f2bf(acc[0]) | ((unsigned)f2bf(acc[1]) << 16);
            o.y = (unsigned)f2bf(acc[2]) | ((unsigned)f2bf(acc[3]) << 16);
            ((uint2*)aggb)[(size_t)dst * 32 + hl] = o;
        }
    }
}

// ---------------------------------------------------------------------------
// GEMM + finalize (verified): out = relu((aggb @ W)/max(deg,1) +
// (deg>0 ? b : 0)) via bf16 MFMA; write-once to d_out.
// ---------------------------------------------------------------------------
__global__ __launch_bounds__(256) void gemm_finalize_kernel(
    const unsigned short* __restrict__ aggb, const unsigned short* __restrict__ Wt,
    const float* __restrict__ b, const int* __restrict__ counts,
    float* __restrict__ out, int n_dst)
{
    __shared__ __align__(16) unsigned char smem[52224];
    unsigned short* Ash = (unsigned short*)smem;                   // [64][LDA]
    unsigned short* Wsh = (unsigned short*)(smem + 64 * LDA * 2);  // [128][LDA]
    float* Csh = (float*)smem;                                     // [64][132]

    const int tid  = threadIdx.x;
    const int lane = tid & 63, wv = tid >> 6;
    const size_t row0 = (size_t)blockIdx.x * 64;

#pragma unroll
    for (int t = 0; t < 4; ++t) {
        int i = tid + t * 256;
        int r = i >> 4, k8 = (i & 15) << 3;
        size_t gr = row0 + r;
        uint4 v = (gr < (size_t)n_dst) ? ((const uint4*)aggb)[gr * 16 + (i & 15)]
                                       : make_uint4(0, 0, 0, 0);
        *(uint4*)&Ash[r * LDA + k8] = v;
    }
#pragma unroll
    for (int t = 0; t < 8; ++t) {
        int i = tid + t * 256;
        int n = i >> 4, k8 = (i & 15) << 3;
        *(uint4*)&Wsh[n * LDA + k8] = ((const uint4*)Wt)[i];
    }
    __syncthreads();

    const int m0 = wv * 16;
    const int fl = lane & 15, quad = lane >> 4;

    f32x4 cacc[8];
#pragma unroll
    for (int n = 0; n < 8; ++n) cacc[n] = (f32x4){0.f, 0.f, 0.f, 0.f};

#pragma unroll
    for (int kc = 0; kc < 128; kc += 32) {
        bf16x8 a = *(const bf16x8*)&Ash[(m0 + fl) * LDA + kc + quad * 8];
#pragma unroll
        for (int n = 0; n < 8; ++n) {
            bf16x8 bf = *(const bf16x8*)&Wsh[(n * 16 + fl) * LDA + kc + quad * 8];
            cacc[n] = __builtin_amdgcn_mfma_f32_16x16x32_bf16(a, bf, cacc[n], 0, 0, 0);
        }
    }

    float inv[4], gate[4];
#pragma unroll
    for (int r = 0; r < 4; ++r) {
        size_t gr = row0 + m0 + quad * 4 + r;
        int dg = (gr < (size_t)n_dst) ? counts[gr * CSTRIDE] : 0;
        inv[r]  = 1.0f / (float)(dg > 1 ? dg : 1);
        gate[r] = (dg > 0) ? 1.0f : 0.0f;
    }
    __syncthreads();   // Ash/Wsh dead; reuse as Csh

#pragma unroll
    for (int n = 0; n < 8; ++n) {
        int col = n * 16 + fl;
        float bc = b[col];
#pragma unroll
        for (int r = 0; r < 4; ++r) {
            float v = cacc[n][r] * inv[r] + bc * gate[r];
            Csh[(m0 + quad * 4 + r) * 132 + col] = fmaxf(v, 0.0f);
        }
    }
    __syncthreads();

#pragma unroll
    for (int t = 0; t < 8; ++t) {
        int i = tid + t * 256;
        int rr = i >> 5, c4 = i & 31;
        size_t gr = row0 + rr;
        if (gr < (size_t)n_dst)
            ((float4*)out)[gr * (D / 4) + c4] = *(float4*)&Csh[rr * 132 + c4 * 4];
    }
}

extern "C" void kernel_launch(void* const* d_in, const int* in_sizes, int n_in,
                              void* d_out, int out_size, void* d_ws, size_t ws_size,
                              hipStream_t stream) {
    const float* H    = (const float*)d_in[0];   // [N_src, 128]
    const float* W    = (const float*)d_in[1];   // [128, 128]
    const float* b    = (const float*)d_in[2];   // [128]
    const int*   esrc = (const int*)d_in[3];     // [E]
    const int*   edst = (const int*)d_in[4];     // [E]
    const int    E     = in_sizes[3];
    const int    n_dst = out_size / D;
    const int    nsrc_elems = in_sizes[0];       // N_src * 128

    float* out = (float*)d_out;

    // ws: Wt | counts(padded) | ovcnt(pad) | ovd | ovs | buckets | aggb | Hb
    char* p = (char*)d_ws;
    unsigned short* Wt = (unsigned short*)p;  p += 128 * 128 * sizeof(unsigned short);
    int* counts = (int*)p;  p += (size_t)n_dst * CSTRIDE * 4;
    int* ovcnt  = (int*)p;  p += 256;            // zeroed together with counts
    int* ovd    = (int*)p;  p += (size_t)OVCAP * 4;
    int* ovs    = (int*)p;  p += (size_t)OVCAP * 4;
    int* buckets= (int*)p;  p += (size_t)n_dst * BCAP * 4;
    size_t agg_off = (((size_t)(p - (char*)d_ws)) + 255) & ~(size_t)255;
    unsigned short* aggb = (unsigned short*)((char*)d_ws + agg_off);
    size_t hb_off = (agg_off + (size_t)n_dst * D * 2 + 255) & ~(size_t)255;
    bool use_bf16h = (ws_size >= hb_off + (size_t)nsrc_elems * 2);
    unsigned* Hb = (unsigned*)((char*)d_ws + hb_off);

    const int nh8 = use_bf16h ? nsrc_elems / 8 : 0;
    int prep_work = nh8 + 16384;
    if (prep_work < E) prep_work = E;

    // Zero padded counts + overflow cursor in one memset (contiguous, ~3.2MB).
    hipMemsetAsync(counts, 0, (size_t)n_dst * CSTRIDE * 4 + 256, stream);

    if (use_bf16h) {
        prep_kernel<true><<<(prep_work + 255) / 256, 256, 0, stream>>>(
            H, Hb, nh8, W, Wt, esrc, edst, E, counts, buckets, ovcnt, ovd, ovs);
        aggregate_kernel<true><<<(n_dst + 3) / 4, 256, 0, stream>>>(
            H, (const uint4*)Hb, buckets, counts, ovcnt, ovd, ovs, aggb, n_dst);
    } else {
        prep_kernel<false><<<(prep_work + 255) / 256, 256, 0, stream>>>(
            H, Hb, nh8, W, Wt, esrc, edst, E, counts, buckets, ovcnt, ovd, ovs);
        aggregate_kernel<false><<<(n_dst + 3) / 4, 256, 0, stream>>>(
            H, nullptr, buckets, counts, ovcnt, ovd, ovs, aggb, n_dst);
    }

    gemm_finalize_kernel<<<(n_dst + 63) / 64, 256, 0, stream>>>(
        aggb, Wt, b, counts, out, n_dst);
}